// Round 5
// baseline (364.369 us; speedup 1.0000x reference)
//
#include <hip/hip_runtime.h>
#include <hip/hip_bf16.h>
#include <cstdint>

// ---------------------------------------------------------------------------
// GAT 2-layer model on MI355X.
// R14 (REGR) / R15 (NEUTRAL) / R16 (NEUTRAL): spmm pinned at ~42us by the
//   random-gather L2-miss path (~2.75 TB/s invariant; fetch = ~8-XCD
//   compulsory replication of hb, 88.6MB ~= 8 x 0.86 x 12.8MB). FROZEN.
// R17 (WIN 290.6->279.1): GEMMs on bf16 MFMA with split precision
//   (hi@hi+hi@lo+lo@hi), absmax unchanged.
// R18: CSR build collapsed to ONE scatter kernel. Degree is Poisson(16)+1
//   (P(deg>64) ~ 1e-15/node), so per-node capacity-64 rows (csrc[d*64+r],
//   25.6MB) are safe. Deletes csr_finalize (391-block serial counting sort,
//   the worst-parallelism kernel in the pipeline) + binned/binCursor/
//   rowbeg/rowend; spmm computes row start arithmetically (node<<6).
// ---------------------------------------------------------------------------

typedef __attribute__((ext_vector_type(8))) short bf16x8;
typedef __attribute__((ext_vector_type(4))) float f32x4;

__device__ __forceinline__ float wave_reduce_sum(float v) {
#pragma unroll
  for (int off = 32; off > 0; off >>= 1) v += __shfl_xor(v, off, 64);
  return v;
}

__device__ __forceinline__ unsigned short f2bf(float f) {  // RNE
  unsigned int u = __float_as_uint(f);
  u += 0x7fffu + ((u >> 16) & 1u);
  return (unsigned short)(u >> 16);
}
__device__ __forceinline__ float bf2f(unsigned short u) {
  return __uint_as_float(((unsigned int)u) << 16);
}

// ---------------- CSR build: single-pass per-node capacity scatter ----------

// csrc[d*64 + r] = s for each edge (incl self-loops); cnt[d] = degree.
__global__ __launch_bounds__(256) void edge_scatter_kernel(
    const int* __restrict__ ei, int E, int M,
    int* __restrict__ cnt, int* __restrict__ csrc) {
  int i = blockIdx.x * 256 + threadIdx.x;
  if (i >= M) return;
  int s, d;
  if (i < E) { s = ei[i]; d = ei[E + i]; } else { s = d = i - E; }
  int r = atomicAdd(&cnt[d], 1);
  if (r < 64) csrc[((size_t)d << 6) + r] = s;
}

// gstart[g] = first node index with batch[node] >= g (batch sorted)
__global__ void bounds_kernel(const int* __restrict__ batch, int* __restrict__ gstart,
                              int N, int G) {
  int g = blockIdx.x * blockDim.x + threadIdx.x;
  if (g > G) return;
  int lo = 0, hi = N;
  while (lo < hi) {
    int mid = (lo + hi) >> 1;
    if (batch[mid] < g) lo = mid + 1;
    else hi = mid;
  }
  gstart[g] = lo;
}

// ---------------- dense compute ----------------

// Split W[k][n] (fp32, row-major KxN=64) into transposed bf16 hi/lo: out[n][k].
__global__ void wsplit_kernel(const float* __restrict__ W, unsigned short* __restrict__ hi,
                              unsigned short* __restrict__ lo, int K) {
  int idx = blockIdx.x * 256 + threadIdx.x;
  if (idx >= K * 64) return;
  int n = idx & 63, k = idx >> 6;
  float v = W[(size_t)k * 64 + n];
  unsigned short h = f2bf(v);
  hi[(size_t)n * K + k] = h;
  lo[(size_t)n * K + k] = f2bf(v - bf2f(h));
}

// hb[N][64] (bf16) = A[N][KDIM] @ W[KDIM][64] via split-bf16 MFMA.
template <int KDIM>
__global__ __launch_bounds__(256) void gemm_mfma(
    const float* __restrict__ A, const unsigned short* __restrict__ Wt_hi,
    const unsigned short* __restrict__ Wt_lo, unsigned short* __restrict__ hb,
    const float* __restrict__ a_src, const float* __restrict__ a_dst,
    float* __restrict__ alsrc, float* __restrict__ aldst, int N) {
  __shared__ unsigned short Ah[64][40], Al[64][40], Bh[64][40], Bl[64][40];
  const int block_m = blockIdx.x * 64;
  const int t = threadIdx.x;
  const int lane = t & 63;
  const int m0 = (t >> 6) * 16;  // wave's row base
  const int lc = lane & 15;      // frag col / A row
  const int lr = lane >> 4;      // k-group / C row-group
  const int srow = t >> 2;            // staging: row (0..63)
  const int skslot = (t & 3) * 8;     // staging: k slot (0,8,16,24)

  f32x4 acc[4] = {};

  for (int kc = 0; kc < KDIM; kc += 32) {
    // ---- stage A chunk (split fp32 -> bf16 hi/lo) ----
    {
      int gn = block_m + srow;
      if (gn >= N) gn = N - 1;
      const float4 v0 = *(const float4*)(A + (size_t)gn * KDIM + kc + skslot);
      const float4 v1 = *(const float4*)(A + (size_t)gn * KDIM + kc + skslot + 4);
      float v[8] = {v0.x, v0.y, v0.z, v0.w, v1.x, v1.y, v1.z, v1.w};
      unsigned short h8[8], l8[8];
#pragma unroll
      for (int j = 0; j < 8; ++j) {
        h8[j] = f2bf(v[j]);
        l8[j] = f2bf(v[j] - bf2f(h8[j]));
      }
      *(uint4*)&Ah[srow][skslot] = *(const uint4*)h8;
      *(uint4*)&Al[srow][skslot] = *(const uint4*)l8;
    }
    // ---- stage W chunk (pre-split, transposed [n][k]) ----
    {
      const uint4 wh = *(const uint4*)(Wt_hi + (size_t)srow * KDIM + kc + skslot);
      const uint4 wl = *(const uint4*)(Wt_lo + (size_t)srow * KDIM + kc + skslot);
      *(uint4*)&Bh[srow][skslot] = wh;
      *(uint4*)&Bl[srow][skslot] = wl;
    }
    __syncthreads();

    const bf16x8 ah = *(const bf16x8*)&Ah[m0 + lc][lr * 8];
    const bf16x8 al = *(const bf16x8*)&Al[m0 + lc][lr * 8];
#pragma unroll
    for (int nf = 0; nf < 4; ++nf) {
      const bf16x8 bh = *(const bf16x8*)&Bh[nf * 16 + lc][lr * 8];
      const bf16x8 bl = *(const bf16x8*)&Bl[nf * 16 + lc][lr * 8];
      acc[nf] = __builtin_amdgcn_mfma_f32_16x16x32_bf16(ah, bh, acc[nf], 0, 0, 0);
      acc[nf] = __builtin_amdgcn_mfma_f32_16x16x32_bf16(ah, bl, acc[nf], 0, 0, 0);
      acc[nf] = __builtin_amdgcn_mfma_f32_16x16x32_bf16(al, bh, acc[nf], 0, 0, 0);
    }
    __syncthreads();
  }

  // ---- epilogue: hb (bf16) + al reductions from fp32 acc ----
  // D[row = m0 + lr*4 + r][col = nf*16 + lc] = acc[nf][r]
  float as4[4], ad4[4];
#pragma unroll
  for (int nf = 0; nf < 4; ++nf) {
    as4[nf] = a_src[nf * 16 + lc];
    ad4[nf] = a_dst[nf * 16 + lc];
  }
#pragma unroll
  for (int r = 0; r < 4; ++r) {
    const int gn = block_m + m0 + lr * 4 + r;
    float ps = 0.f, pd = 0.f;
#pragma unroll
    for (int nf = 0; nf < 4; ++nf) {
      const float v = acc[nf][r];
      if (gn < N) hb[(size_t)gn * 64 + nf * 16 + lc] = f2bf(v);
      ps += v * as4[nf];
      pd += v * ad4[nf];
    }
#pragma unroll
    for (int off = 1; off < 16; off <<= 1) {
      ps += __shfl_xor(ps, off, 64);
      pd += __shfl_xor(pd, off, 64);
    }
    if (lc == 0 && gn < N) {
      alsrc[gn] = ps;
      aldst[gn] = pd;
    }
  }
}

// Fused no-max softmax + spmm (R16 form, frozen: structurally pinned ~42us).
// R18: row start is arithmetic (node<<6), end from cnt[] (capacity-64 rows).
template <int ELU>
__global__ __launch_bounds__(256) void spmm_fused_kernel(
    const int* __restrict__ cnt, const int* __restrict__ csrc,
    const float* __restrict__ alsrc, const float* __restrict__ aldst,
    const unsigned short* __restrict__ hb, const float* __restrict__ bias,
    float* __restrict__ outbuf, int N) {
  const int t = threadIdx.x;
  const int l = t & 15;        // slot within group
  const int gb = t & 48;       // group base lane within wave
  const int half = l >> 3;     // which edge of the pair this lane serves
  const int f0 = (l & 7) * 8;  // first feature owned by this lane
  const int node = blockIdx.x * 16 + (t >> 4);
  if (node >= N) return;
  const int start = node << 6;
  const int end = start + min(cnt[node], 64);
  const float ad = aldst[node];

  float ssum = 0.f;
  float acc[8] = {};

  int i0 = start + l;
  bool v0 = i0 < end;
  int s = v0 ? csrc[i0] : 0;
  float w;
  {
    float e = alsrc[s] + ad;
    e = (e > 0.f) ? e : 0.2f * e;  // leaky_relu 0.2
    w = v0 ? __expf(fminf(e, 80.f)) : 0.f;
  }

  for (int base = start; base < end; base += 16) {
    int in = base + 16 + l;
    bool vn = in < end;
    int sn = vn ? csrc[in] : 0;
    float aln = alsrc[sn];

    uint4 u[8];
#pragma unroll
    for (int j = 0; j < 8; ++j) {
      int sj = __shfl(s, gb + 2 * j + half, 64);
      u[j] = *(const uint4*)(hb + (size_t)sj * 64 + f0);
    }

    ssum += w;
#pragma unroll
    for (int j = 0; j < 8; ++j) {
      float wj = __shfl(w, gb + 2 * j + half, 64);
      acc[0] += wj * __uint_as_float(u[j].x << 16);
      acc[1] += wj * __uint_as_float(u[j].x & 0xFFFF0000u);
      acc[2] += wj * __uint_as_float(u[j].y << 16);
      acc[3] += wj * __uint_as_float(u[j].y & 0xFFFF0000u);
      acc[4] += wj * __uint_as_float(u[j].z << 16);
      acc[5] += wj * __uint_as_float(u[j].z & 0xFFFF0000u);
      acc[6] += wj * __uint_as_float(u[j].w << 16);
      acc[7] += wj * __uint_as_float(u[j].w & 0xFFFF0000u);
    }

    float en = aln + ad;
    en = (en > 0.f) ? en : 0.2f * en;
    w = vn ? __expf(fminf(en, 80.f)) : 0.f;
    s = sn;
  }

#pragma unroll
  for (int k = 0; k < 8; ++k) acc[k] += __shfl_xor(acc[k], 8, 64);
#pragma unroll
  for (int off = 1; off < 16; off <<= 1) ssum += __shfl_xor(ssum, off, 64);

  if (half == 0) {
    float inv = 1.0f / ssum;  // >= 1 edge (self-loop)
    float r[8];
#pragma unroll
    for (int k = 0; k < 8; ++k) r[k] = acc[k] * inv;
    if (ELU) {
      const float4 b40 = *(const float4*)(bias + f0);
      const float4 b41 = *(const float4*)(bias + f0 + 4);
      r[0] += b40.x; r[1] += b40.y; r[2] += b40.z; r[3] += b40.w;
      r[4] += b41.x; r[5] += b41.y; r[6] += b41.z; r[7] += b41.w;
#pragma unroll
      for (int k = 0; k < 8; ++k) r[k] = (r[k] > 0.f) ? r[k] : expm1f(r[k]);
    }
    *(float4*)(outbuf + (size_t)node * 64 + f0) = make_float4(r[0], r[1], r[2], r[3]);
    *(float4*)(outbuf + (size_t)node * 64 + f0 + 4) = make_float4(r[4], r[5], r[6], r[7]);
  }
}

// bias + ELU + hierarchical mean-pool accumulation (layer 2)
__global__ __launch_bounds__(256) void post_pool_kernel(
    const float* __restrict__ acc, const float* __restrict__ bias,
    const int* __restrict__ batch, float* __restrict__ pool, int N) {
  __shared__ float4 red4[16][17];
  __shared__ int sB[16];
  __shared__ int uni;
  const int t = threadIdx.x;
  const int ln = t >> 4;
  const int f4 = t & 15;
  const int base = blockIdx.x * 16;
  const int node = base + ln;

  if (t < 16) {
    int nn = base + t;
    sB[t] = (nn < N) ? batch[nn] : -1;
  }
  __syncthreads();
  if (t == 0) {
    int u = (base + 15 < N);
    for (int i = 1; i < 16; i++) u &= (sB[i] == sB[0]);
    uni = u;
  }

  float4 v = make_float4(0.f, 0.f, 0.f, 0.f);
  if (node < N) {
    v = *(const float4*)(acc + ((size_t)node * 16 + f4) * 4);
    const float4 b4 = *(const float4*)(bias + f4 * 4);
    v.x += b4.x; v.y += b4.y; v.z += b4.z; v.w += b4.w;
    v.x = (v.x > 0.f) ? v.x : expm1f(v.x);
    v.y = (v.y > 0.f) ? v.y : expm1f(v.y);
    v.z = (v.z > 0.f) ? v.z : expm1f(v.z);
    v.w = (v.w > 0.f) ? v.w : expm1f(v.w);
  }
  red4[ln][f4] = v;
  __syncthreads();

  if (t < 64) {
    const float* rf = (const float*)red4;  // row stride 68 floats
    if (uni) {
      float s = 0.f;
#pragma unroll
      for (int n = 0; n < 16; n++) s += rf[n * 68 + t];
      atomicAdd(&pool[(size_t)sB[0] * 64 + t], s);
    } else {
      for (int n = 0; n < 16; n++) {
        int g = sB[n];
        if (g >= 0) atomicAdd(&pool[(size_t)g * 64 + t], rf[n * 68 + t]);
      }
    }
  }
}

// out[g] = (pool[g,:]/cnt[g]) . Wfc + bfc ; cnt from sorted-batch bounds.
__global__ void final_kernel(const float* __restrict__ pool, const int* __restrict__ gstart,
                             const float* __restrict__ Wfc, const float* __restrict__ bfc,
                             float* __restrict__ out, int G) {
  int wid = (blockIdx.x * blockDim.x + threadIdx.x) >> 6;
  int lane = threadIdx.x & 63;
  if (wid >= G) return;
  float c = (float)max(gstart[wid + 1] - gstart[wid], 1);
  float v = pool[(size_t)wid * 64 + lane] * (1.0f / c) * Wfc[lane];
  v = wave_reduce_sum(v);
  if (lane == 0) out[wid] = v + bfc[0];
}

// ---------------------------------------------------------------------------

extern "C" void kernel_launch(void* const* d_in, const int* in_sizes, int n_in,
                              void* d_out, int out_size, void* d_ws, size_t ws_size,
                              hipStream_t stream) {
  const float* x     = (const float*)d_in[0];
  const int*   ei    = (const int*)d_in[1];
  const int*   batch = (const int*)d_in[2];
  const float* W1    = (const float*)d_in[3];
  const float* asrc1 = (const float*)d_in[4];
  const float* adst1 = (const float*)d_in[5];
  const float* b1    = (const float*)d_in[6];
  const float* W2    = (const float*)d_in[7];
  const float* asrc2 = (const float*)d_in[8];
  const float* adst2 = (const float*)d_in[9];
  const float* b2    = (const float*)d_in[10];
  const float* Wfc   = (const float*)d_in[11];
  const float* bfc   = (const float*)d_in[12];
  float* out = (float*)d_out;

  const int N = in_sizes[0] / 128;  // 100000
  const int E = in_sizes[1] / 2;    // 1600000
  const int G = 256;
  const int M = E + N;              // edges incl self-loops

  // workspace carve (256B aligned)
  char* p = (char*)d_ws;
  auto alloc = [&](size_t bytes) {
    char* r = p;
    p += (bytes + 255) & ~size_t(255);
    return r;
  };
  float*          h1e    = (float*)alloc((size_t)N * 64 * 4);
  float*          accbuf = (float*)alloc((size_t)N * 64 * 4);
  unsigned short* hb     = (unsigned short*)alloc((size_t)N * 64 * 2);
  float* alsrc  = (float*)alloc((size_t)N * 4);
  float* aldst  = (float*)alloc((size_t)N * 4);
  int*   cnt    = (int*)alloc((size_t)N * 4);
  int*   csrc   = (int*)alloc((size_t)N * 64 * 4);  // capacity-64 rows
  float* pool   = (float*)alloc((size_t)G * 64 * 4);
  int*   gstart = (int*)alloc((size_t)(G + 1) * 4);
  unsigned short* w1thi = (unsigned short*)alloc((size_t)64 * 128 * 2);
  unsigned short* w1tlo = (unsigned short*)alloc((size_t)64 * 128 * 2);
  unsigned short* w2thi = (unsigned short*)alloc((size_t)64 * 64 * 2);
  unsigned short* w2tlo = (unsigned short*)alloc((size_t)64 * 64 * 2);

  // ---- CSR build (single-pass scatter) + graph bounds + weight presplit ----
  hipMemsetAsync(cnt, 0, (size_t)N * 4, stream);
  edge_scatter_kernel<<<(M + 255) / 256, 256, 0, stream>>>(ei, E, M, cnt, csrc);
  bounds_kernel<<<2, 256, 0, stream>>>(batch, gstart, N, G);
  wsplit_kernel<<<(128 * 64 + 255) / 256, 256, 0, stream>>>(W1, w1thi, w1tlo, 128);
  wsplit_kernel<<<(64 * 64 + 255) / 256, 256, 0, stream>>>(W2, w2thi, w2tlo, 64);

  // ---- layer 1 ----
  gemm_mfma<128><<<(N + 63) / 64, 256, 0, stream>>>(x, w1thi, w1tlo, hb, asrc1, adst1,
                                                    alsrc, aldst, N);
  spmm_fused_kernel<1><<<(N + 15) / 16, 256, 0, stream>>>(cnt, csrc, alsrc, aldst, hb,
                                                          b1, h1e, N);

  // ---- layer 2 ----
  gemm_mfma<64><<<(N + 63) / 64, 256, 0, stream>>>(h1e, w2thi, w2tlo, hb, asrc2, adst2,
                                                   alsrc, aldst, N);
  spmm_fused_kernel<0><<<(N + 15) / 16, 256, 0, stream>>>(cnt, csrc, alsrc, aldst, hb,
                                                          nullptr, accbuf, N);
  hipMemsetAsync(pool, 0, (size_t)G * 64 * 4, stream);
  post_pool_kernel<<<(N + 15) / 16, 256, 0, stream>>>(accbuf, b2, batch, pool, N);

  // ---- readout ----
  final_kernel<<<(G * 64 + 255) / 256, 256, 0, stream>>>(pool, gstart, Wfc, bfc, out, G);
}

// Round 6
// 304.706 us; speedup vs baseline: 1.1958x; 1.1958x over previous
//
#include <hip/hip_runtime.h>
#include <hip/hip_bf16.h>
#include <cstdint>

// ---------------------------------------------------------------------------
// GAT 2-layer model on MI355X.
// R14-R16: spmm pinned at ~42us by the random-gather L2-miss path
//   (~2.75 TB/s invariant; fetch ~= 8-XCD replication of hb). FROZEN.
// R17 (WIN 290.6->279.1): GEMMs on bf16 MFMA, split precision
//   (hi@hi+hi@lo+lo@hi), absmax unchanged.
// R18 (REGRESSION 279->364): single-pass scatter CSR: 1.7M random 4B
//   stores+atomics -> 99.6MB write-amplification, 130us, VALUBusy 0.5%.
//   Lesson: scatter must stay window-confined (L2-resident), as in the
//   binned build. CSR build reverted to R13's proven form.
// R19: gemm_mfma made LDS-free: A fragment = 2 float4/lane from own row,
//   split in-register; B (W^T, <=32KB, L2-resident) read directly from
//   global in the verified fragment layout. Removes the entire per-chunk
//   LDS round-trip + 2 syncthreads (R17 gained only 11.5us -> gemms were
//   staging-bound, not MFMA-bound).
// ---------------------------------------------------------------------------

#define BIN_SHIFT 8
#define BIN_NODES 256
#define BIN_CAP 6144
#define PLACE_CHUNK 2048

typedef __attribute__((ext_vector_type(8))) short bf16x8;
typedef __attribute__((ext_vector_type(4))) float f32x4;

__device__ __forceinline__ float wave_reduce_sum(float v) {
#pragma unroll
  for (int off = 32; off > 0; off >>= 1) v += __shfl_xor(v, off, 64);
  return v;
}

__device__ __forceinline__ unsigned short f2bf(float f) {  // RNE
  unsigned int u = __float_as_uint(f);
  u += 0x7fffu + ((u >> 16) & 1u);
  return (unsigned short)(u >> 16);
}
__device__ __forceinline__ float bf2f(unsigned short u) {
  return __uint_as_float(((unsigned int)u) << 16);
}

// ---------------- CSR build (capacity-binned, single ei pass) ----------------

__global__ __launch_bounds__(256) void bin_place_kernel(
    const int* __restrict__ ei, int E, int M, int NB,
    int* __restrict__ binCursor, unsigned int* __restrict__ binned) {
  __shared__ int cur[512];
  __shared__ int res[512];
  const int t = threadIdx.x;
  const int cbase = blockIdx.x * PLACE_CHUNK;

  for (int i = t; i < NB; i += 256) cur[i] = 0;
  __syncthreads();

  unsigned int pk[PLACE_CHUNK / 256];
  int br[PLACE_CHUNK / 256];
#pragma unroll
  for (int j = 0; j < PLACE_CHUNK / 256; ++j) {
    int i = cbase + t + j * 256;
    if (i < M) {
      int s, d;
      if (i < E) { s = ei[i]; d = ei[E + i]; } else { s = d = i - E; }
      int b = d >> BIN_SHIFT;
      int r = atomicAdd(&cur[b], 1);
      pk[j] = ((unsigned int)(d & (BIN_NODES - 1)) << 24) | (unsigned int)s;
      br[j] = (b << 16) | r;  // b<512 (15b), r<2048 (16b)
    } else {
      br[j] = -1;
    }
  }
  __syncthreads();
  for (int i = t; i < NB; i += 256) {
    int c = cur[i];
    res[i] = c ? atomicAdd(&binCursor[i], c) : 0;
  }
  __syncthreads();
#pragma unroll
  for (int j = 0; j < PLACE_CHUNK / 256; ++j) {
    if (br[j] >= 0) {
      int b = br[j] >> 16;
      int pos = res[b] + (br[j] & 0xFFFF);
      if (pos < BIN_CAP) binned[(size_t)b * BIN_CAP + pos] = pk[j];
    }
  }
}

__global__ __launch_bounds__(256) void csr_finalize_kernel(
    const unsigned int* __restrict__ binned, const int* __restrict__ binCursor,
    int* __restrict__ rowbeg, int* __restrict__ rowend, int* __restrict__ csrc,
    int N, int NB) {
  __shared__ int cnt[256];
  __shared__ int off[256];
  __shared__ int wsum[4];
  const int b = blockIdx.x;
  const int t = threadIdx.x;
  const int nodeBase = b << BIN_SHIFT;
  const int eBase = b * BIN_CAP;
  const int cntE = binCursor[b];

  cnt[t] = 0;
  __syncthreads();
  for (int i = t; i < cntE; i += 256) {
    atomicAdd(&cnt[binned[eBase + i] >> 24], 1);
  }
  __syncthreads();
  int v = cnt[t];
  {  // exclusive scan cnt -> off
    int lane = t & 63, wv = t >> 6;
    int x = v;
#pragma unroll
    for (int o = 1; o < 64; o <<= 1) {
      int u = __shfl_up(x, o, 64);
      if (lane >= o) x += u;
    }
    if (lane == 63) wsum[wv] = x;
    __syncthreads();
    int woff = 0;
    for (int j = 0; j < wv; j++) woff += wsum[j];
    off[t] = woff + x - v;
  }
  __syncthreads();
  int node = nodeBase + t;
  if (node < N) {
    rowbeg[node] = eBase + off[t];
    rowend[node] = eBase + off[t] + v;
  }
  cnt[t] = off[t];  // reuse as cursor
  __syncthreads();
  for (int i = t; i < cntE; i += 256) {
    unsigned int pk = binned[eBase + i];
    int r = atomicAdd(&cnt[pk >> 24], 1);
    csrc[eBase + r] = (int)(pk & 0xFFFFFFu);
  }
}

// gstart[g] = first node index with batch[node] >= g (batch sorted)
__global__ void bounds_kernel(const int* __restrict__ batch, int* __restrict__ gstart,
                              int N, int G) {
  int g = blockIdx.x * blockDim.x + threadIdx.x;
  if (g > G) return;
  int lo = 0, hi = N;
  while (lo < hi) {
    int mid = (lo + hi) >> 1;
    if (batch[mid] < g) lo = mid + 1;
    else hi = mid;
  }
  gstart[g] = lo;
}

// ---------------- dense compute ----------------

// Split W[k][n] (fp32, row-major KxN=64) into transposed bf16 hi/lo: out[n][k].
__global__ void wsplit_kernel(const float* __restrict__ W, unsigned short* __restrict__ hi,
                              unsigned short* __restrict__ lo, int K) {
  int idx = blockIdx.x * 256 + threadIdx.x;
  if (idx >= K * 64) return;
  int n = idx & 63, k = idx >> 6;
  float v = W[(size_t)k * 64 + n];
  unsigned short h = f2bf(v);
  hi[(size_t)n * K + k] = h;
  lo[(size_t)n * K + k] = f2bf(v - bf2f(h));
}

// hb[N][64] (bf16) = A[N][KDIM] @ W[KDIM][64] via split-bf16 MFMA.
// R19: LDS-free. Per 32-K chunk each lane loads its own A fragment
// (2xfloat4 of row block_m+m0+lc), splits to bf16 hi/lo in-register, and
// loads B fragments (W^T pre-split, L2/L1-resident) directly from global in
// the verified layout (lane lc holds W^T row nf*16+lc, k-slice lr*8..+7).
// No barriers; occupancy limited only by VGPRs. Fused al epilogue.
template <int KDIM>
__global__ __launch_bounds__(256) void gemm_mfma(
    const float* __restrict__ A, const unsigned short* __restrict__ Wt_hi,
    const unsigned short* __restrict__ Wt_lo, unsigned short* __restrict__ hb,
    const float* __restrict__ a_src, const float* __restrict__ a_dst,
    float* __restrict__ alsrc, float* __restrict__ aldst, int N) {
  const int block_m = blockIdx.x * 64;
  const int t = threadIdx.x;
  const int lane = t & 63;
  const int m0 = (t >> 6) * 16;  // wave's row base
  const int lc = lane & 15;      // frag col / A row
  const int lr = lane >> 4;      // k-group / C row-group

  int ga = block_m + m0 + lc;    // A row this lane streams
  if (ga >= N) ga = N - 1;
  const float* Arow = A + (size_t)ga * KDIM;

  f32x4 acc[4] = {};

#pragma unroll
  for (int kc = 0; kc < KDIM; kc += 32) {
    // ---- A fragment: load 8 fp32, split to bf16 hi/lo in-register ----
    const float4 v0 = *(const float4*)(Arow + kc + lr * 8);
    const float4 v1 = *(const float4*)(Arow + kc + lr * 8 + 4);
    const float v[8] = {v0.x, v0.y, v0.z, v0.w, v1.x, v1.y, v1.z, v1.w};
    unsigned short h8[8], l8[8];
#pragma unroll
    for (int j = 0; j < 8; ++j) {
      h8[j] = f2bf(v[j]);
      l8[j] = f2bf(v[j] - bf2f(h8[j]));
    }
    const bf16x8 ah = *(const bf16x8*)h8;
    const bf16x8 al = *(const bf16x8*)l8;

    // ---- B fragments straight from global (L2-resident, 16-32KB) ----
#pragma unroll
    for (int nf = 0; nf < 4; ++nf) {
      const size_t boff = (size_t)(nf * 16 + lc) * KDIM + kc + lr * 8;
      const bf16x8 bh = *(const bf16x8*)(Wt_hi + boff);
      const bf16x8 bl = *(const bf16x8*)(Wt_lo + boff);
      acc[nf] = __builtin_amdgcn_mfma_f32_16x16x32_bf16(ah, bh, acc[nf], 0, 0, 0);
      acc[nf] = __builtin_amdgcn_mfma_f32_16x16x32_bf16(ah, bl, acc[nf], 0, 0, 0);
      acc[nf] = __builtin_amdgcn_mfma_f32_16x16x32_bf16(al, bh, acc[nf], 0, 0, 0);
    }
  }

  // ---- epilogue: hb (bf16) + al reductions from fp32 acc ----
  // D[row = m0 + lr*4 + r][col = nf*16 + lc] = acc[nf][r]
  float as4[4], ad4[4];
#pragma unroll
  for (int nf = 0; nf < 4; ++nf) {
    as4[nf] = a_src[nf * 16 + lc];
    ad4[nf] = a_dst[nf * 16 + lc];
  }
#pragma unroll
  for (int r = 0; r < 4; ++r) {
    const int gn = block_m + m0 + lr * 4 + r;
    float ps = 0.f, pd = 0.f;
#pragma unroll
    for (int nf = 0; nf < 4; ++nf) {
      const float vv = acc[nf][r];
      if (gn < N) hb[(size_t)gn * 64 + nf * 16 + lc] = f2bf(vv);
      ps += vv * as4[nf];
      pd += vv * ad4[nf];
    }
#pragma unroll
    for (int off = 1; off < 16; off <<= 1) {
      ps += __shfl_xor(ps, off, 64);
      pd += __shfl_xor(pd, off, 64);
    }
    if (lc == 0 && gn < N) {
      alsrc[gn] = ps;
      aldst[gn] = pd;
    }
  }
}

// Fused no-max softmax + spmm (R16 form, frozen: structurally pinned ~42us).
template <int ELU>
__global__ __launch_bounds__(256) void spmm_fused_kernel(
    const int* __restrict__ rowbeg, const int* __restrict__ rowend,
    const int* __restrict__ csrc,
    const float* __restrict__ alsrc, const float* __restrict__ aldst,
    const unsigned short* __restrict__ hb, const float* __restrict__ bias,
    float* __restrict__ outbuf, int N) {
  const int t = threadIdx.x;
  const int l = t & 15;        // slot within group
  const int gb = t & 48;       // group base lane within wave
  const int half = l >> 3;     // which edge of the pair this lane serves
  const int f0 = (l & 7) * 8;  // first feature owned by this lane
  const int node = blockIdx.x * 16 + (t >> 4);
  if (node >= N) return;
  const int start = rowbeg[node];
  const int end = rowend[node];
  const float ad = aldst[node];

  float ssum = 0.f;
  float acc[8] = {};

  int i0 = start + l;
  bool v0 = i0 < end;
  int s = v0 ? csrc[i0] : 0;
  float w;
  {
    float e = alsrc[s] + ad;
    e = (e > 0.f) ? e : 0.2f * e;  // leaky_relu 0.2
    w = v0 ? __expf(fminf(e, 80.f)) : 0.f;
  }

  for (int base = start; base < end; base += 16) {
    int in = base + 16 + l;
    bool vn = in < end;
    int sn = vn ? csrc[in] : 0;
    float aln = alsrc[sn];

    uint4 u[8];
#pragma unroll
    for (int j = 0; j < 8; ++j) {
      int sj = __shfl(s, gb + 2 * j + half, 64);
      u[j] = *(const uint4*)(hb + (size_t)sj * 64 + f0);
    }

    ssum += w;
#pragma unroll
    for (int j = 0; j < 8; ++j) {
      float wj = __shfl(w, gb + 2 * j + half, 64);
      acc[0] += wj * __uint_as_float(u[j].x << 16);
      acc[1] += wj * __uint_as_float(u[j].x & 0xFFFF0000u);
      acc[2] += wj * __uint_as_float(u[j].y << 16);
      acc[3] += wj * __uint_as_float(u[j].y & 0xFFFF0000u);
      acc[4] += wj * __uint_as_float(u[j].z << 16);
      acc[5] += wj * __uint_as_float(u[j].z & 0xFFFF0000u);
      acc[6] += wj * __uint_as_float(u[j].w << 16);
      acc[7] += wj * __uint_as_float(u[j].w & 0xFFFF0000u);
    }

    float en = aln + ad;
    en = (en > 0.f) ? en : 0.2f * en;
    w = vn ? __expf(fminf(en, 80.f)) : 0.f;
    s = sn;
  }

#pragma unroll
  for (int k = 0; k < 8; ++k) acc[k] += __shfl_xor(acc[k], 8, 64);
#pragma unroll
  for (int off = 1; off < 16; off <<= 1) ssum += __shfl_xor(ssum, off, 64);

  if (half == 0) {
    float inv = 1.0f / ssum;  // >= 1 edge (self-loop)
    float r[8];
#pragma unroll
    for (int k = 0; k < 8; ++k) r[k] = acc[k] * inv;
    if (ELU) {
      const float4 b40 = *(const float4*)(bias + f0);
      const float4 b41 = *(const float4*)(bias + f0 + 4);
      r[0] += b40.x; r[1] += b40.y; r[2] += b40.z; r[3] += b40.w;
      r[4] += b41.x; r[5] += b41.y; r[6] += b41.z; r[7] += b41.w;
#pragma unroll
      for (int k = 0; k < 8; ++k) r[k] = (r[k] > 0.f) ? r[k] : expm1f(r[k]);
    }
    *(float4*)(outbuf + (size_t)node * 64 + f0) = make_float4(r[0], r[1], r[2], r[3]);
    *(float4*)(outbuf + (size_t)node * 64 + f0 + 4) = make_float4(r[4], r[5], r[6], r[7]);
  }
}

// bias + ELU + hierarchical mean-pool accumulation (layer 2)
__global__ __launch_bounds__(256) void post_pool_kernel(
    const float* __restrict__ acc, const float* __restrict__ bias,
    const int* __restrict__ batch, float* __restrict__ pool, int N) {
  __shared__ float4 red4[16][17];
  __shared__ int sB[16];
  __shared__ int uni;
  const int t = threadIdx.x;
  const int ln = t >> 4;
  const int f4 = t & 15;
  const int base = blockIdx.x * 16;
  const int node = base + ln;

  if (t < 16) {
    int nn = base + t;
    sB[t] = (nn < N) ? batch[nn] : -1;
  }
  __syncthreads();
  if (t == 0) {
    int u = (base + 15 < N);
    for (int i = 1; i < 16; i++) u &= (sB[i] == sB[0]);
    uni = u;
  }

  float4 v = make_float4(0.f, 0.f, 0.f, 0.f);
  if (node < N) {
    v = *(const float4*)(acc + ((size_t)node * 16 + f4) * 4);
    const float4 b4 = *(const float4*)(bias + f4 * 4);
    v.x += b4.x; v.y += b4.y; v.z += b4.z; v.w += b4.w;
    v.x = (v.x > 0.f) ? v.x : expm1f(v.x);
    v.y = (v.y > 0.f) ? v.y : expm1f(v.y);
    v.z = (v.z > 0.f) ? v.z : expm1f(v.z);
    v.w = (v.w > 0.f) ? v.w : expm1f(v.w);
  }
  red4[ln][f4] = v;
  __syncthreads();

  if (t < 64) {
    const float* rf = (const float*)red4;  // row stride 68 floats
    if (uni) {
      float s = 0.f;
#pragma unroll
      for (int n = 0; n < 16; n++) s += rf[n * 68 + t];
      atomicAdd(&pool[(size_t)sB[0] * 64 + t], s);
    } else {
      for (int n = 0; n < 16; n++) {
        int g = sB[n];
        if (g >= 0) atomicAdd(&pool[(size_t)g * 64 + t], rf[n * 68 + t]);
      }
    }
  }
}

// out[g] = (pool[g,:]/cnt[g]) . Wfc + bfc ; cnt from sorted-batch bounds.
__global__ void final_kernel(const float* __restrict__ pool, const int* __restrict__ gstart,
                             const float* __restrict__ Wfc, const float* __restrict__ bfc,
                             float* __restrict__ out, int G) {
  int wid = (blockIdx.x * blockDim.x + threadIdx.x) >> 6;
  int lane = threadIdx.x & 63;
  if (wid >= G) return;
  float c = (float)max(gstart[wid + 1] - gstart[wid], 1);
  float v = pool[(size_t)wid * 64 + lane] * (1.0f / c) * Wfc[lane];
  v = wave_reduce_sum(v);
  if (lane == 0) out[wid] = v + bfc[0];
}

// ---------------------------------------------------------------------------

extern "C" void kernel_launch(void* const* d_in, const int* in_sizes, int n_in,
                              void* d_out, int out_size, void* d_ws, size_t ws_size,
                              hipStream_t stream) {
  const float* x     = (const float*)d_in[0];
  const int*   ei    = (const int*)d_in[1];
  const int*   batch = (const int*)d_in[2];
  const float* W1    = (const float*)d_in[3];
  const float* asrc1 = (const float*)d_in[4];
  const float* adst1 = (const float*)d_in[5];
  const float* b1    = (const float*)d_in[6];
  const float* W2    = (const float*)d_in[7];
  const float* asrc2 = (const float*)d_in[8];
  const float* adst2 = (const float*)d_in[9];
  const float* b2    = (const float*)d_in[10];
  const float* Wfc   = (const float*)d_in[11];
  const float* bfc   = (const float*)d_in[12];
  float* out = (float*)d_out;

  const int N = in_sizes[0] / 128;  // 100000
  const int E = in_sizes[1] / 2;    // 1600000
  const int G = 256;
  const int M = E + N;              // edges incl self-loops
  const int NB = (N + BIN_NODES - 1) >> BIN_SHIFT;  // 391 bins

  // workspace carve (256B aligned)
  char* p = (char*)d_ws;
  auto alloc = [&](size_t bytes) {
    char* r = p;
    p += (bytes + 255) & ~size_t(255);
    return r;
  };
  float*          h1e    = (float*)alloc((size_t)N * 64 * 4);
  float*          accbuf = (float*)alloc((size_t)N * 64 * 4);
  unsigned short* hb     = (unsigned short*)alloc((size_t)N * 64 * 2);
  float* alsrc  = (float*)alloc((size_t)N * 4);
  float* aldst  = (float*)alloc((size_t)N * 4);
  int*   rowbeg = (int*)alloc((size_t)N * 4);
  int*   rowend = (int*)alloc((size_t)N * 4);
  int*   csrc   = (int*)alloc((size_t)NB * BIN_CAP * 4);
  unsigned int* binned = (unsigned int*)alloc((size_t)NB * BIN_CAP * 4);
  int*   binCursor = (int*)alloc((size_t)NB * 4);
  float* pool   = (float*)alloc((size_t)G * 64 * 4);
  int*   gstart = (int*)alloc((size_t)(G + 1) * 4);
  unsigned short* w1thi = (unsigned short*)alloc((size_t)64 * 128 * 2);
  unsigned short* w1tlo = (unsigned short*)alloc((size_t)64 * 128 * 2);
  unsigned short* w2thi = (unsigned short*)alloc((size_t)64 * 64 * 2);
  unsigned short* w2tlo = (unsigned short*)alloc((size_t)64 * 64 * 2);

  // ---- CSR build (capacity-binned) + graph bounds + weight presplit ----
  hipMemsetAsync(binCursor, 0, (size_t)NB * 4, stream);
  bin_place_kernel<<<(M + PLACE_CHUNK - 1) / PLACE_CHUNK, 256, 0, stream>>>(
      ei, E, M, NB, binCursor, binned);
  csr_finalize_kernel<<<NB, 256, 0, stream>>>(binned, binCursor, rowbeg, rowend,
                                              csrc, N, NB);
  bounds_kernel<<<2, 256, 0, stream>>>(batch, gstart, N, G);
  wsplit_kernel<<<(128 * 64 + 255) / 256, 256, 0, stream>>>(W1, w1thi, w1tlo, 128);
  wsplit_kernel<<<(64 * 64 + 255) / 256, 256, 0, stream>>>(W2, w2thi, w2tlo, 64);

  // ---- layer 1 ----
  gemm_mfma<128><<<(N + 63) / 64, 256, 0, stream>>>(x, w1thi, w1tlo, hb, asrc1, adst1,
                                                    alsrc, aldst, N);
  spmm_fused_kernel<1><<<(N + 15) / 16, 256, 0, stream>>>(rowbeg, rowend, csrc, alsrc,
                                                          aldst, hb, b1, h1e, N);

  // ---- layer 2 ----
  gemm_mfma<64><<<(N + 63) / 64, 256, 0, stream>>>(h1e, w2thi, w2tlo, hb, asrc2, adst2,
                                                   alsrc, aldst, N);
  spmm_fused_kernel<0><<<(N + 15) / 16, 256, 0, stream>>>(rowbeg, rowend, csrc, alsrc,
                                                          aldst, hb, nullptr, accbuf, N);
  hipMemsetAsync(pool, 0, (size_t)G * 64 * 4, stream);
  post_pool_kernel<<<(N + 15) / 16, 256, 0, stream>>>(accbuf, b2, batch, pool, N);

  // ---- readout ----
  final_kernel<<<(G * 64 + 255) / 256, 256, 0, stream>>>(pool, gstart, Wfc, bfc, out, G);
}

// Round 7
// 268.415 us; speedup vs baseline: 1.3575x; 1.1352x over previous
//
#include <hip/hip_runtime.h>
#include <hip/hip_bf16.h>
#include <cstdint>

// ---------------------------------------------------------------------------
// GAT 2-layer model on MI355X.
// R14-R16: spmm pinned at ~42us by the random-gather L2-miss path
//   (~2.75 TB/s invariant; fetch ~= 8-XCD replication of hb). FROZEN.
// R17 (WIN 290.6->279.1): GEMMs on bf16 MFMA via LDS staging, split
//   precision (hi@hi+hi@lo+lo@hi), absmax unchanged.
// R18 (REGR 279->364): device-wide scatter CSR -> 100MB write-amplification.
//   Lesson: scatter must stay window-confined (L2-resident bins).
// R19 (REGR 279->305): LDS-free gemm: full unroll -> ~40 in-flight VMEM,
//   strided A reads; LDS staging's barrier-paced pipeline was load-bearing.
//   gemm reverted to R17's exact form.
// R20: (a) setup fused into ONE kernel (binCursor zero + pool zero + bounds
//   + wsplit W1/W2): 13 -> 9 launches. (b) csr_finalize at 512 threads
//   (same window-confined bins; both edge passes 2x more parallel).
// ---------------------------------------------------------------------------

#define BIN_SHIFT 8
#define BIN_NODES 256
#define BIN_CAP 6144
#define PLACE_CHUNK 2048

typedef __attribute__((ext_vector_type(8))) short bf16x8;
typedef __attribute__((ext_vector_type(4))) float f32x4;

__device__ __forceinline__ float wave_reduce_sum(float v) {
#pragma unroll
  for (int off = 32; off > 0; off >>= 1) v += __shfl_xor(v, off, 64);
  return v;
}

__device__ __forceinline__ unsigned short f2bf(float f) {  // RNE
  unsigned int u = __float_as_uint(f);
  u += 0x7fffu + ((u >> 16) & 1u);
  return (unsigned short)(u >> 16);
}
__device__ __forceinline__ float bf2f(unsigned short u) {
  return __uint_as_float(((unsigned int)u) << 16);
}

// ---------------- fused setup: memsets + bounds + weight presplit ----------

// Grid layout (256 threads/block):
//   [0,32)    wsplit W1 (128x64)
//   [32,48)   wsplit W2 (64x64)
//   [48,50)   bounds (gstart, G+1=257 entries)
//   [50,52)   zero binCursor (NB=391)
//   [52,116)  zero pool (G*64 = 16384 floats)
__global__ __launch_bounds__(256) void setup_kernel(
    const float* __restrict__ W1, unsigned short* __restrict__ w1thi,
    unsigned short* __restrict__ w1tlo, const float* __restrict__ W2,
    unsigned short* __restrict__ w2thi, unsigned short* __restrict__ w2tlo,
    const int* __restrict__ batch, int* __restrict__ gstart,
    int* __restrict__ binCursor, float* __restrict__ pool, int N, int G, int NB) {
  const int b = blockIdx.x;
  const int t = threadIdx.x;
  if (b < 32) {
    int idx = b * 256 + t;  // < 8192 = 128*64
    int n = idx & 63, k = idx >> 6;
    float v = W1[(size_t)k * 64 + n];
    unsigned short h = f2bf(v);
    w1thi[(size_t)n * 128 + k] = h;
    w1tlo[(size_t)n * 128 + k] = f2bf(v - bf2f(h));
  } else if (b < 48) {
    int idx = (b - 32) * 256 + t;  // < 4096 = 64*64
    int n = idx & 63, k = idx >> 6;
    float v = W2[(size_t)k * 64 + n];
    unsigned short h = f2bf(v);
    w2thi[(size_t)n * 64 + k] = h;
    w2tlo[(size_t)n * 64 + k] = f2bf(v - bf2f(h));
  } else if (b < 50) {
    int g = (b - 48) * 256 + t;
    if (g <= G) {
      int lo = 0, hi = N;
      while (lo < hi) {
        int mid = (lo + hi) >> 1;
        if (batch[mid] < g) lo = mid + 1;
        else hi = mid;
      }
      gstart[g] = lo;
    }
  } else if (b < 52) {
    int i = (b - 50) * 256 + t;
    if (i < NB) binCursor[i] = 0;
  } else {
    int i = (b - 52) * 256 + t;  // < 16384
    pool[i] = 0.f;
  }
}

// ---------------- CSR build (capacity-binned, single ei pass) ----------------

__global__ __launch_bounds__(256) void bin_place_kernel(
    const int* __restrict__ ei, int E, int M, int NB,
    int* __restrict__ binCursor, unsigned int* __restrict__ binned) {
  __shared__ int cur[512];
  __shared__ int res[512];
  const int t = threadIdx.x;
  const int cbase = blockIdx.x * PLACE_CHUNK;

  for (int i = t; i < NB; i += 256) cur[i] = 0;
  __syncthreads();

  unsigned int pk[PLACE_CHUNK / 256];
  int br[PLACE_CHUNK / 256];
#pragma unroll
  for (int j = 0; j < PLACE_CHUNK / 256; ++j) {
    int i = cbase + t + j * 256;
    if (i < M) {
      int s, d;
      if (i < E) { s = ei[i]; d = ei[E + i]; } else { s = d = i - E; }
      int b = d >> BIN_SHIFT;
      int r = atomicAdd(&cur[b], 1);
      pk[j] = ((unsigned int)(d & (BIN_NODES - 1)) << 24) | (unsigned int)s;
      br[j] = (b << 16) | r;  // b<512 (15b), r<2048 (16b)
    } else {
      br[j] = -1;
    }
  }
  __syncthreads();
  for (int i = t; i < NB; i += 256) {
    int c = cur[i];
    res[i] = c ? atomicAdd(&binCursor[i], c) : 0;
  }
  __syncthreads();
#pragma unroll
  for (int j = 0; j < PLACE_CHUNK / 256; ++j) {
    if (br[j] >= 0) {
      int b = br[j] >> 16;
      int pos = res[b] + (br[j] & 0xFFFF);
      if (pos < BIN_CAP) binned[(size_t)b * BIN_CAP + pos] = pk[j];
    }
  }
}

// R20: 512 threads/block (both edge passes 2x more parallel; scan barriers
// hoisted outside thread guards).
__global__ __launch_bounds__(512) void csr_finalize_kernel(
    const unsigned int* __restrict__ binned, const int* __restrict__ binCursor,
    int* __restrict__ rowbeg, int* __restrict__ rowend, int* __restrict__ csrc,
    int N, int NB) {
  __shared__ int cnt[256];
  __shared__ int off[256];
  __shared__ int wsum[8];
  const int b = blockIdx.x;
  const int t = threadIdx.x;
  const int nodeBase = b << BIN_SHIFT;
  const int eBase = b * BIN_CAP;
  const int cntE = binCursor[b];

  if (t < 256) cnt[t] = 0;
  __syncthreads();
  for (int i = t; i < cntE; i += 512) {
    atomicAdd(&cnt[binned[eBase + i] >> 24], 1);
  }
  __syncthreads();
  const int lane = t & 63, wv = t >> 6;
  int v = (t < 256) ? cnt[t] : 0;
  int x = v;
#pragma unroll
  for (int o = 1; o < 64; o <<= 1) {
    int u = __shfl_up(x, o, 64);
    if (lane >= o) x += u;
  }
  if (t < 256 && lane == 63) wsum[wv] = x;
  __syncthreads();
  if (t < 256) {
    int woff = 0;
    for (int j = 0; j < wv; j++) woff += wsum[j];
    const int o = woff + x - v;
    off[t] = o;
    int node = nodeBase + t;
    if (node < N) {
      rowbeg[node] = eBase + o;
      rowend[node] = eBase + o + v;
    }
    cnt[t] = o;  // reuse as cursor
  }
  __syncthreads();
  for (int i = t; i < cntE; i += 512) {
    unsigned int pk = binned[eBase + i];
    int r = atomicAdd(&cnt[pk >> 24], 1);
    csrc[eBase + r] = (int)(pk & 0xFFFFFFu);
  }
}

// ---------------- dense compute ----------------

// hb[N][64] (bf16) = A[N][KDIM] @ W[KDIM][64] via split-bf16 MFMA.
// R17 form (proven): LDS-staged A (split on the fly) + pre-split W^T,
// barrier-paced; fused al epilogue from exact fp32 accumulators.
template <int KDIM>
__global__ __launch_bounds__(256) void gemm_mfma(
    const float* __restrict__ A, const unsigned short* __restrict__ Wt_hi,
    const unsigned short* __restrict__ Wt_lo, unsigned short* __restrict__ hb,
    const float* __restrict__ a_src, const float* __restrict__ a_dst,
    float* __restrict__ alsrc, float* __restrict__ aldst, int N) {
  __shared__ unsigned short Ah[64][40], Al[64][40], Bh[64][40], Bl[64][40];
  const int block_m = blockIdx.x * 64;
  const int t = threadIdx.x;
  const int lane = t & 63;
  const int m0 = (t >> 6) * 16;  // wave's row base
  const int lc = lane & 15;      // frag col / A row
  const int lr = lane >> 4;      // k-group / C row-group
  const int srow = t >> 2;            // staging: row (0..63)
  const int skslot = (t & 3) * 8;     // staging: k slot (0,8,16,24)

  f32x4 acc[4] = {};

  for (int kc = 0; kc < KDIM; kc += 32) {
    // ---- stage A chunk (split fp32 -> bf16 hi/lo) ----
    {
      int gn = block_m + srow;
      if (gn >= N) gn = N - 1;
      const float4 v0 = *(const float4*)(A + (size_t)gn * KDIM + kc + skslot);
      const float4 v1 = *(const float4*)(A + (size_t)gn * KDIM + kc + skslot + 4);
      float v[8] = {v0.x, v0.y, v0.z, v0.w, v1.x, v1.y, v1.z, v1.w};
      unsigned short h8[8], l8[8];
#pragma unroll
      for (int j = 0; j < 8; ++j) {
        h8[j] = f2bf(v[j]);
        l8[j] = f2bf(v[j] - bf2f(h8[j]));
      }
      *(uint4*)&Ah[srow][skslot] = *(const uint4*)h8;
      *(uint4*)&Al[srow][skslot] = *(const uint4*)l8;
    }
    // ---- stage W chunk (pre-split, transposed [n][k]) ----
    {
      const uint4 wh = *(const uint4*)(Wt_hi + (size_t)srow * KDIM + kc + skslot);
      const uint4 wl = *(const uint4*)(Wt_lo + (size_t)srow * KDIM + kc + skslot);
      *(uint4*)&Bh[srow][skslot] = wh;
      *(uint4*)&Bl[srow][skslot] = wl;
    }
    __syncthreads();

    const bf16x8 ah = *(const bf16x8*)&Ah[m0 + lc][lr * 8];
    const bf16x8 al = *(const bf16x8*)&Al[m0 + lc][lr * 8];
#pragma unroll
    for (int nf = 0; nf < 4; ++nf) {
      const bf16x8 bh = *(const bf16x8*)&Bh[nf * 16 + lc][lr * 8];
      const bf16x8 bl = *(const bf16x8*)&Bl[nf * 16 + lc][lr * 8];
      acc[nf] = __builtin_amdgcn_mfma_f32_16x16x32_bf16(ah, bh, acc[nf], 0, 0, 0);
      acc[nf] = __builtin_amdgcn_mfma_f32_16x16x32_bf16(ah, bl, acc[nf], 0, 0, 0);
      acc[nf] = __builtin_amdgcn_mfma_f32_16x16x32_bf16(al, bh, acc[nf], 0, 0, 0);
    }
    __syncthreads();
  }

  // ---- epilogue: hb (bf16) + al reductions from fp32 acc ----
  // D[row = m0 + lr*4 + r][col = nf*16 + lc] = acc[nf][r]
  float as4[4], ad4[4];
#pragma unroll
  for (int nf = 0; nf < 4; ++nf) {
    as4[nf] = a_src[nf * 16 + lc];
    ad4[nf] = a_dst[nf * 16 + lc];
  }
#pragma unroll
  for (int r = 0; r < 4; ++r) {
    const int gn = block_m + m0 + lr * 4 + r;
    float ps = 0.f, pd = 0.f;
#pragma unroll
    for (int nf = 0; nf < 4; ++nf) {
      const float v = acc[nf][r];
      if (gn < N) hb[(size_t)gn * 64 + nf * 16 + lc] = f2bf(v);
      ps += v * as4[nf];
      pd += v * ad4[nf];
    }
#pragma unroll
    for (int off = 1; off < 16; off <<= 1) {
      ps += __shfl_xor(ps, off, 64);
      pd += __shfl_xor(pd, off, 64);
    }
    if (lc == 0 && gn < N) {
      alsrc[gn] = ps;
      aldst[gn] = pd;
    }
  }
}

// Fused no-max softmax + spmm (R16 form, frozen: structurally pinned ~42us).
template <int ELU>
__global__ __launch_bounds__(256) void spmm_fused_kernel(
    const int* __restrict__ rowbeg, const int* __restrict__ rowend,
    const int* __restrict__ csrc,
    const float* __restrict__ alsrc, const float* __restrict__ aldst,
    const unsigned short* __restrict__ hb, const float* __restrict__ bias,
    float* __restrict__ outbuf, int N) {
  const int t = threadIdx.x;
  const int l = t & 15;        // slot within group
  const int gb = t & 48;       // group base lane within wave
  const int half = l >> 3;     // which edge of the pair this lane serves
  const int f0 = (l & 7) * 8;  // first feature owned by this lane
  const int node = blockIdx.x * 16 + (t >> 4);
  if (node >= N) return;
  const int start = rowbeg[node];
  const int end = rowend[node];
  const float ad = aldst[node];

  float ssum = 0.f;
  float acc[8] = {};

  int i0 = start + l;
  bool v0 = i0 < end;
  int s = v0 ? csrc[i0] : 0;
  float w;
  {
    float e = alsrc[s] + ad;
    e = (e > 0.f) ? e : 0.2f * e;  // leaky_relu 0.2
    w = v0 ? __expf(fminf(e, 80.f)) : 0.f;
  }

  for (int base = start; base < end; base += 16) {
    int in = base + 16 + l;
    bool vn = in < end;
    int sn = vn ? csrc[in] : 0;
    float aln = alsrc[sn];

    uint4 u[8];
#pragma unroll
    for (int j = 0; j < 8; ++j) {
      int sj = __shfl(s, gb + 2 * j + half, 64);
      u[j] = *(const uint4*)(hb + (size_t)sj * 64 + f0);
    }

    ssum += w;
#pragma unroll
    for (int j = 0; j < 8; ++j) {
      float wj = __shfl(w, gb + 2 * j + half, 64);
      acc[0] += wj * __uint_as_float(u[j].x << 16);
      acc[1] += wj * __uint_as_float(u[j].x & 0xFFFF0000u);
      acc[2] += wj * __uint_as_float(u[j].y << 16);
      acc[3] += wj * __uint_as_float(u[j].y & 0xFFFF0000u);
      acc[4] += wj * __uint_as_float(u[j].z << 16);
      acc[5] += wj * __uint_as_float(u[j].z & 0xFFFF0000u);
      acc[6] += wj * __uint_as_float(u[j].w << 16);
      acc[7] += wj * __uint_as_float(u[j].w & 0xFFFF0000u);
    }

    float en = aln + ad;
    en = (en > 0.f) ? en : 0.2f * en;
    w = vn ? __expf(fminf(en, 80.f)) : 0.f;
    s = sn;
  }

#pragma unroll
  for (int k = 0; k < 8; ++k) acc[k] += __shfl_xor(acc[k], 8, 64);
#pragma unroll
  for (int off = 1; off < 16; off <<= 1) ssum += __shfl_xor(ssum, off, 64);

  if (half == 0) {
    float inv = 1.0f / ssum;  // >= 1 edge (self-loop)
    float r[8];
#pragma unroll
    for (int k = 0; k < 8; ++k) r[k] = acc[k] * inv;
    if (ELU) {
      const float4 b40 = *(const float4*)(bias + f0);
      const float4 b41 = *(const float4*)(bias + f0 + 4);
      r[0] += b40.x; r[1] += b40.y; r[2] += b40.z; r[3] += b40.w;
      r[4] += b41.x; r[5] += b41.y; r[6] += b41.z; r[7] += b41.w;
#pragma unroll
      for (int k = 0; k < 8; ++k) r[k] = (r[k] > 0.f) ? r[k] : expm1f(r[k]);
    }
    *(float4*)(outbuf + (size_t)node * 64 + f0) = make_float4(r[0], r[1], r[2], r[3]);
    *(float4*)(outbuf + (size_t)node * 64 + f0 + 4) = make_float4(r[4], r[5], r[6], r[7]);
  }
}

// bias + ELU + hierarchical mean-pool accumulation (layer 2)
__global__ __launch_bounds__(256) void post_pool_kernel(
    const float* __restrict__ acc, const float* __restrict__ bias,
    const int* __restrict__ batch, float* __restrict__ pool, int N) {
  __shared__ float4 red4[16][17];
  __shared__ int sB[16];
  __shared__ int uni;
  const int t = threadIdx.x;
  const int ln = t >> 4;
  const int f4 = t & 15;
  const int base = blockIdx.x * 16;
  const int node = base + ln;

  if (t < 16) {
    int nn = base + t;
    sB[t] = (nn < N) ? batch[nn] : -1;
  }
  __syncthreads();
  if (t == 0) {
    int u = (base + 15 < N);
    for (int i = 1; i < 16; i++) u &= (sB[i] == sB[0]);
    uni = u;
  }

  float4 v = make_float4(0.f, 0.f, 0.f, 0.f);
  if (node < N) {
    v = *(const float4*)(acc + ((size_t)node * 16 + f4) * 4);
    const float4 b4 = *(const float4*)(bias + f4 * 4);
    v.x += b4.x; v.y += b4.y; v.z += b4.z; v.w += b4.w;
    v.x = (v.x > 0.f) ? v.x : expm1f(v.x);
    v.y = (v.y > 0.f) ? v.y : expm1f(v.y);
    v.z = (v.z > 0.f) ? v.z : expm1f(v.z);
    v.w = (v.w > 0.f) ? v.w : expm1f(v.w);
  }
  red4[ln][f4] = v;
  __syncthreads();

  if (t < 64) {
    const float* rf = (const float*)red4;  // row stride 68 floats
    if (uni) {
      float s = 0.f;
#pragma unroll
      for (int n = 0; n < 16; n++) s += rf[n * 68 + t];
      atomicAdd(&pool[(size_t)sB[0] * 64 + t], s);
    } else {
      for (int n = 0; n < 16; n++) {
        int g = sB[n];
        if (g >= 0) atomicAdd(&pool[(size_t)g * 64 + t], rf[n * 68 + t]);
      }
    }
  }
}

// out[g] = (pool[g,:]/cnt[g]) . Wfc + bfc ; cnt from sorted-batch bounds.
__global__ void final_kernel(const float* __restrict__ pool, const int* __restrict__ gstart,
                             const float* __restrict__ Wfc, const float* __restrict__ bfc,
                             float* __restrict__ out, int G) {
  int wid = (blockIdx.x * blockDim.x + threadIdx.x) >> 6;
  int lane = threadIdx.x & 63;
  if (wid >= G) return;
  float c = (float)max(gstart[wid + 1] - gstart[wid], 1);
  float v = pool[(size_t)wid * 64 + lane] * (1.0f / c) * Wfc[lane];
  v = wave_reduce_sum(v);
  if (lane == 0) out[wid] = v + bfc[0];
}

// ---------------------------------------------------------------------------

extern "C" void kernel_launch(void* const* d_in, const int* in_sizes, int n_in,
                              void* d_out, int out_size, void* d_ws, size_t ws_size,
                              hipStream_t stream) {
  const float* x     = (const float*)d_in[0];
  const int*   ei    = (const int*)d_in[1];
  const int*   batch = (const int*)d_in[2];
  const float* W1    = (const float*)d_in[3];
  const float* asrc1 = (const float*)d_in[4];
  const float* adst1 = (const float*)d_in[5];
  const float* b1    = (const float*)d_in[6];
  const float* W2    = (const float*)d_in[7];
  const float* asrc2 = (const float*)d_in[8];
  const float* adst2 = (const float*)d_in[9];
  const float* b2    = (const float*)d_in[10];
  const float* Wfc   = (const float*)d_in[11];
  const float* bfc   = (const float*)d_in[12];
  float* out = (float*)d_out;

  const int N = in_sizes[0] / 128;  // 100000
  const int E = in_sizes[1] / 2;    // 1600000
  const int G = 256;
  const int M = E + N;              // edges incl self-loops
  const int NB = (N + BIN_NODES - 1) >> BIN_SHIFT;  // 391 bins

  // workspace carve (256B aligned)
  char* p = (char*)d_ws;
  auto alloc = [&](size_t bytes) {
    char* r = p;
    p += (bytes + 255) & ~size_t(255);
    return r;
  };
  float*          h1e    = (float*)alloc((size_t)N * 64 * 4);
  float*          accbuf = (float*)alloc((size_t)N * 64 * 4);
  unsigned short* hb     = (unsigned short*)alloc((size_t)N * 64 * 2);
  float* alsrc  = (float*)alloc((size_t)N * 4);
  float* aldst  = (float*)alloc((size_t)N * 4);
  int*   rowbeg = (int*)alloc((size_t)N * 4);
  int*   rowend = (int*)alloc((size_t)N * 4);
  int*   csrc   = (int*)alloc((size_t)NB * BIN_CAP * 4);
  unsigned int* binned = (unsigned int*)alloc((size_t)NB * BIN_CAP * 4);
  int*   binCursor = (int*)alloc((size_t)NB * 4);
  float* pool   = (float*)alloc((size_t)G * 64 * 4);
  int*   gstart = (int*)alloc((size_t)(G + 1) * 4);
  unsigned short* w1thi = (unsigned short*)alloc((size_t)64 * 128 * 2);
  unsigned short* w1tlo = (unsigned short*)alloc((size_t)64 * 128 * 2);
  unsigned short* w2thi = (unsigned short*)alloc((size_t)64 * 64 * 2);
  unsigned short* w2tlo = (unsigned short*)alloc((size_t)64 * 64 * 2);

  // ---- fused setup + CSR build ----
  setup_kernel<<<116, 256, 0, stream>>>(W1, w1thi, w1tlo, W2, w2thi, w2tlo,
                                        batch, gstart, binCursor, pool, N, G, NB);
  bin_place_kernel<<<(M + PLACE_CHUNK - 1) / PLACE_CHUNK, 256, 0, stream>>>(
      ei, E, M, NB, binCursor, binned);
  csr_finalize_kernel<<<NB, 512, 0, stream>>>(binned, binCursor, rowbeg, rowend,
                                              csrc, N, NB);

  // ---- layer 1 ----
  gemm_mfma<128><<<(N + 63) / 64, 256, 0, stream>>>(x, w1thi, w1tlo, hb, asrc1, adst1,
                                                    alsrc, aldst, N);
  spmm_fused_kernel<1><<<(N + 15) / 16, 256, 0, stream>>>(rowbeg, rowend, csrc, alsrc,
                                                          aldst, hb, b1, h1e, N);

  // ---- layer 2 ----
  gemm_mfma<64><<<(N + 63) / 64, 256, 0, stream>>>(h1e, w2thi, w2tlo, hb, asrc2, adst2,
                                                   alsrc, aldst, N);
  spmm_fused_kernel<0><<<(N + 15) / 16, 256, 0, stream>>>(rowbeg, rowend, csrc, alsrc,
                                                          aldst, hb, nullptr, accbuf, N);
  post_pool_kernel<<<(N + 15) / 16, 256, 0, stream>>>(accbuf, b2, batch, pool, N);

  // ---- readout ----
  final_kernel<<<(G * 64 + 255) / 256, 256, 0, stream>>>(pool, gstart, Wfc, bfc, out, G);
}